// Round 1
// baseline (214.220 us; speedup 1.0000x reference)
//
#include <hip/hip_runtime.h>
#include <stdint.h>

// ContrastiveLoss (SimCLR NT-Xent), B=4096, D=128, T=0.5
// loss = (1/2B) * sum_k log(denom_k)  -  (1/(B*T)) * sum_i dot(z_i, z_j_i)
// denom_k = sum_{l != k} exp(sim[k,l]/T),  sim = Z Z^T, Z = normalized [2B x 128]

#define TEMP 0.5f
// exp(x/T) = exp2(x * log2(e)/T); T=0.5 -> scale = 2*log2(e)
#define EXP2_SCALE 2.885390081777927f

typedef __bf16 bf16_t;
typedef bf16_t bf16x8 __attribute__((ext_vector_type(8)));
typedef float floatx4 __attribute__((ext_vector_type(4)));

__device__ __forceinline__ unsigned short f32_to_bf16(float f) {
    union { float f; uint32_t u; } v; v.f = f;
    uint32_t u = v.u;
    // round-to-nearest-even (inputs are finite, no NaN handling needed)
    uint32_t r = (u + 0x7FFFu + ((u >> 16) & 1u)) >> 16;
    return (unsigned short)r;
}

// ---------------------------------------------------------------------------
// Kernel 1: per-row L2 normalize of proj_1 and proj_2, write bf16 reps[2B][128]
// to workspace; also compute positives dot(z_i, z_j_i) exactly in fp32 and
// atomically accumulate the positive term of the loss into out[0].
// One wave (64 lanes) per row-pair i; 2 floats per lane (D=128).
// ---------------------------------------------------------------------------
__global__ __launch_bounds__(256) void norm_pos_kernel(
        const float* __restrict__ p1, const float* __restrict__ p2,
        unsigned short* __restrict__ reps, float* __restrict__ out, int B) {
    int wave = threadIdx.x >> 6;
    int lane = threadIdx.x & 63;
    int i = blockIdx.x * 4 + wave;
    if (i >= B) return;

    const float2* r1 = (const float2*)(p1 + (size_t)i * 128);
    const float2* r2 = (const float2*)(p2 + (size_t)i * 128);
    float2 a = r1[lane];
    float2 b = r2[lane];
    float ss1 = a.x * a.x + a.y * a.y;
    float ss2 = b.x * b.x + b.y * b.y;
    float d   = a.x * b.x + a.y * b.y;
    #pragma unroll
    for (int off = 32; off > 0; off >>= 1) {
        ss1 += __shfl_xor(ss1, off);
        ss2 += __shfl_xor(ss2, off);
        d   += __shfl_xor(d,   off);
    }
    float rn1 = rsqrtf(fmaxf(ss1, 1e-24f));
    float rn2 = rsqrtf(fmaxf(ss2, 1e-24f));

    ushort2* z1 = (ushort2*)reps + (size_t)i * 64;
    ushort2* z2 = (ushort2*)reps + (size_t)(B + i) * 64;
    z1[lane] = make_ushort2(f32_to_bf16(a.x * rn1), f32_to_bf16(a.y * rn1));
    z2[lane] = make_ushort2(f32_to_bf16(b.x * rn2), f32_to_bf16(b.y * rn2));

    if (lane == 0) {
        float pos = d * rn1 * rn2;
        // positive term: each i contributes -pos/T twice, averaged over 2B
        atomicAdd(out, -pos / ((float)B * TEMP));
    }
}

// ---------------------------------------------------------------------------
// Kernel 2: 64x64 sim tile per block via mfma_f32_16x16x32_bf16 (K=128 fully
// staged), exp2 with diag mask, per-row partial sums -> atomicAdd rowsum[].
// LDS rows padded +8 bf16 (stride 136) -> b128 reads land 2-way/balanced.
// A-frag layout: A[m=lane&15][k=(lane>>4)*8+j]; B symmetric (B operand rows
// are Z rows too since sim = Z Z^T). C/D: col=lane&15, row=(lane>>4)*4+reg.
// (sim symmetric => a row/col-swapped C/D interpretation is still correct.)
// ---------------------------------------------------------------------------
__global__ __launch_bounds__(256) void simexp_kernel(
        const unsigned short* __restrict__ reps,
        float* __restrict__ rowsum, int N2) {
    __shared__ unsigned short As[64][136];
    __shared__ unsigned short Bs[64][136];

    const int rowBase = blockIdx.y * 64;
    const int colBase = blockIdx.x * 64;
    const int tid = threadIdx.x;

    // stage A (rows rowBase..+63) and B (rows colBase..+63): 16 uint4 per row
    const uint4* g = (const uint4*)reps;
    #pragma unroll
    for (int idx = tid; idx < 1024; idx += 256) {
        int r = idx >> 4, c = idx & 15;
        uint4 va = g[(size_t)(rowBase + r) * 16 + c];
        *(uint4*)&As[r][c * 8] = va;
        uint4 vb = g[(size_t)(colBase + r) * 16 + c];
        *(uint4*)&Bs[r][c * 8] = vb;
    }
    __syncthreads();

    const int wave = tid >> 6;
    const int lane = tid & 63;
    const int quad = lane >> 4;
    const int l16  = lane & 15;

    floatx4 acc[4];
    #pragma unroll
    for (int ct = 0; ct < 4; ++ct) acc[ct] = (floatx4){0.f, 0.f, 0.f, 0.f};

    #pragma unroll
    for (int ks = 0; ks < 4; ++ks) {
        bf16x8 af = *(const bf16x8*)&As[wave * 16 + l16][quad * 8 + ks * 32];
        #pragma unroll
        for (int ct = 0; ct < 4; ++ct) {
            bf16x8 bfr = *(const bf16x8*)&Bs[ct * 16 + l16][quad * 8 + ks * 32];
            acc[ct] = __builtin_amdgcn_mfma_f32_16x16x32_bf16(af, bfr, acc[ct], 0, 0, 0);
        }
    }

    // exp + per-row partial sums. D element (ct, reg) is at
    // global row = rowBase + wave*16 + quad*4 + reg, col = colBase + ct*16 + l16
    float rs[4] = {0.f, 0.f, 0.f, 0.f};
    #pragma unroll
    for (int ct = 0; ct < 4; ++ct) {
        #pragma unroll
        for (int reg = 0; reg < 4; ++reg) {
            int r = rowBase + wave * 16 + quad * 4 + reg;
            int c = colBase + ct * 16 + l16;
            float e = (r == c) ? 0.f : exp2f(acc[ct][reg] * EXP2_SCALE);
            rs[reg] += e;
        }
    }
    // reduce across the 16 lanes of each quad (bits 0..3 of lane id)
    #pragma unroll
    for (int off = 1; off < 16; off <<= 1) {
        #pragma unroll
        for (int reg = 0; reg < 4; ++reg)
            rs[reg] += __shfl_xor(rs[reg], off);
    }
    if (l16 == 0) {
        #pragma unroll
        for (int reg = 0; reg < 4; ++reg)
            atomicAdd(&rowsum[rowBase + wave * 16 + quad * 4 + reg], rs[reg]);
    }
}

// ---------------------------------------------------------------------------
// Kernel 3: out += (1/2B) * sum_k log(rowsum[k])
// ---------------------------------------------------------------------------
__global__ __launch_bounds__(256) void finalize_kernel(
        const float* __restrict__ rowsum, float* __restrict__ out, int N2) {
    int k = blockIdx.x * blockDim.x + threadIdx.x;
    float v = 0.f;
    if (k < N2) v = logf(rowsum[k]) * (1.0f / (float)N2);
    #pragma unroll
    for (int off = 32; off > 0; off >>= 1) v += __shfl_xor(v, off);
    if ((threadIdx.x & 63) == 0) atomicAdd(out, v);
}

extern "C" void kernel_launch(void* const* d_in, const int* in_sizes, int n_in,
                              void* d_out, int out_size, void* d_ws, size_t ws_size,
                              hipStream_t stream) {
    const float* p1 = (const float*)d_in[0];
    const float* p2 = (const float*)d_in[1];
    float* out = (float*)d_out;

    const int B  = in_sizes[0] / 128;   // 4096
    const int N2 = 2 * B;               // 8192

    // workspace layout: [reps bf16: N2*128*2 B][rowsum fp32: N2*4 B]
    unsigned short* reps = (unsigned short*)d_ws;
    float* rowsum = (float*)((char*)d_ws + (size_t)N2 * 128 * sizeof(unsigned short));

    hipMemsetAsync(out, 0, sizeof(float), stream);
    hipMemsetAsync(rowsum, 0, (size_t)N2 * sizeof(float), stream);

    norm_pos_kernel<<<dim3((B + 3) / 4), dim3(256), 0, stream>>>(p1, p2, reps, out, B);

    dim3 grid(N2 / 64, N2 / 64);  // 128 x 128 = 16384 blocks
    simexp_kernel<<<grid, dim3(256), 0, stream>>>(reps, rowsum, N2);

    finalize_kernel<<<dim3((N2 + 255) / 256), dim3(256), 0, stream>>>(rowsum, out, N2);
}

// Round 2
// 118.012 us; speedup vs baseline: 1.8152x; 1.8152x over previous
//
#include <hip/hip_runtime.h>
#include <stdint.h>

// ContrastiveLoss (SimCLR NT-Xent), B=4096, D=128, T=0.5
// loss = (1/2B) * sum_k log(denom_k)  -  (1/(B*T)) * sum_i dot(z_i, z_j_i)

#define TEMP 0.5f
// exp(x/T) = exp2(x * log2(e)/T); T=0.5 -> scale = 2*log2(e)
#define EXP2_SCALE 2.885390081777927f

typedef __bf16 bf16_t;
typedef bf16_t bf16x8 __attribute__((ext_vector_type(8)));
typedef float floatx4 __attribute__((ext_vector_type(4)));

__device__ __forceinline__ unsigned short f32_to_bf16(float f) {
    union { float f; uint32_t u; } v; v.f = f;
    uint32_t u = v.u;
    uint32_t r = (u + 0x7FFFu + ((u >> 16) & 1u)) >> 16;  // RNE
    return (unsigned short)r;
}

__device__ __forceinline__ bf16x8 as_bf16x8(uint4 v) {
    union { uint4 u; bf16x8 b; } c; c.u = v; return c.b;
}

// ---------------------------------------------------------------------------
// Kernel 1: per-row L2 normalize, bf16 reps[2B][128] to ws; pos[i] = dot(z_i,z_j)
// exact fp32, stored (NO atomics — round-1's 4096 same-address atomicAdds
// serialized at L2).
// ---------------------------------------------------------------------------
__global__ __launch_bounds__(256) void norm_pos_kernel(
        const float* __restrict__ p1, const float* __restrict__ p2,
        unsigned short* __restrict__ reps, float* __restrict__ pos, int B) {
    int wave = threadIdx.x >> 6;
    int lane = threadIdx.x & 63;
    int i = blockIdx.x * 4 + wave;
    if (i >= B) return;

    const float2* r1 = (const float2*)(p1 + (size_t)i * 128);
    const float2* r2 = (const float2*)(p2 + (size_t)i * 128);
    float2 a = r1[lane];
    float2 b = r2[lane];
    float ss1 = a.x * a.x + a.y * a.y;
    float ss2 = b.x * b.x + b.y * b.y;
    float d   = a.x * b.x + a.y * b.y;
    #pragma unroll
    for (int off = 32; off > 0; off >>= 1) {
        ss1 += __shfl_xor(ss1, off);
        ss2 += __shfl_xor(ss2, off);
        d   += __shfl_xor(d,   off);
    }
    float rn1 = rsqrtf(fmaxf(ss1, 1e-24f));
    float rn2 = rsqrtf(fmaxf(ss2, 1e-24f));

    ushort2* z1 = (ushort2*)reps + (size_t)i * 64;
    ushort2* z2 = (ushort2*)reps + (size_t)(B + i) * 64;
    z1[lane] = make_ushort2(f32_to_bf16(a.x * rn1), f32_to_bf16(a.y * rn1));
    z2[lane] = make_ushort2(f32_to_bf16(b.x * rn2), f32_to_bf16(b.y * rn2));

    if (lane == 0) pos[i] = d * rn1 * rn2;
}

// ---------------------------------------------------------------------------
// Kernel 2: LDS-free sim+exp. Block = 4 waves; wave owns 64 rows as 4 A-tiles
// of 16 rows held in registers (16x16x32 bf16 MFMA, layout verified round 1:
// A[m=l16][k=quad*8+ks*32+j], frag bytes at row*256 + ks*64 + quad*16).
// Block covers a 256-row panel x 256-col strip; B-frags read straight from
// global (reps is 2 MB, L2-resident; 4 waves share B-frags via L1). Each
// B-frag feeds 4 MFMAs. rowsum partials kept in registers across the strip,
// one atomicAdd per row per block (spread over 8192 addresses).
// ---------------------------------------------------------------------------
__global__ __launch_bounds__(256) void simexp_kernel(
        const unsigned short* __restrict__ reps,
        float* __restrict__ rowsum) {
    const int tid  = threadIdx.x;
    const int wave = tid >> 6;
    const int lane = tid & 63;
    const int quad = lane >> 4;
    const int l16  = lane & 15;

    const int rowWave = blockIdx.y * 256 + wave * 64;  // this wave's 64 rows
    const int colBase = blockIdx.x * 256;              // this block's col strip

    const uint4* g = (const uint4*)reps;  // 16 uint4 per 256-B row

    // A-fragments for 4 row-tiles x 4 k-steps (64 VGPRs), read once
    bf16x8 a[4][4];
    #pragma unroll
    for (int t = 0; t < 4; ++t)
        #pragma unroll
        for (int ks = 0; ks < 4; ++ks)
            a[t][ks] = as_bf16x8(g[(size_t)(rowWave + t * 16 + l16) * 16 + ks * 4 + quad]);

    float rs[4][4];
    #pragma unroll
    for (int t = 0; t < 4; ++t)
        #pragma unroll
        for (int r = 0; r < 4; ++r) rs[t][r] = 0.f;

    #pragma unroll 2
    for (int ctile = 0; ctile < 16; ++ctile) {
        const int colT = colBase + ctile * 16;
        bf16x8 b[4];
        #pragma unroll
        for (int ks = 0; ks < 4; ++ks)
            b[ks] = as_bf16x8(g[(size_t)(colT + l16) * 16 + ks * 4 + quad]);

        floatx4 acc[4];
        #pragma unroll
        for (int t = 0; t < 4; ++t) acc[t] = (floatx4){0.f, 0.f, 0.f, 0.f};

        #pragma unroll
        for (int ks = 0; ks < 4; ++ks)
            #pragma unroll
            for (int t = 0; t < 4; ++t)
                acc[t] = __builtin_amdgcn_mfma_f32_16x16x32_bf16(a[t][ks], b[ks], acc[t], 0, 0, 0);

        const int c = colT + l16;  // this lane's output column
        #pragma unroll
        for (int t = 0; t < 4; ++t) {
            #pragma unroll
            for (int reg = 0; reg < 4; ++reg) {
                int r = rowWave + t * 16 + quad * 4 + reg;
                float e = (r == c) ? 0.f : exp2f(acc[t][reg] * EXP2_SCALE);
                rs[t][reg] += e;
            }
        }
    }

    // reduce across the 16 columns (l16 lanes) of each quad
    #pragma unroll
    for (int off = 1; off < 16; off <<= 1)
        #pragma unroll
        for (int t = 0; t < 4; ++t)
            #pragma unroll
            for (int reg = 0; reg < 4; ++reg)
                rs[t][reg] += __shfl_xor(rs[t][reg], off);

    if (l16 == 0) {
        #pragma unroll
        for (int t = 0; t < 4; ++t)
            #pragma unroll
            for (int reg = 0; reg < 4; ++reg)
                atomicAdd(&rowsum[rowWave + t * 16 + quad * 4 + reg], rs[t][reg]);
    }
}

// ---------------------------------------------------------------------------
// Kernel 3: single block; out[0] = mean(log(rowsum)) - sum(pos)/(B*T).
// Direct store — no atomics, no out-memset needed.
// ---------------------------------------------------------------------------
__global__ __launch_bounds__(1024) void finalize_kernel(
        const float* __restrict__ rowsum, const float* __restrict__ pos,
        float* __restrict__ out, int N2, int B) {
    float v = 0.f;
    for (int k = threadIdx.x; k < N2; k += 1024) v += logf(rowsum[k]);
    float p = 0.f;
    for (int i = threadIdx.x; i < B; i += 1024) p += pos[i];
    float local = v * (1.0f / (float)N2) - p * (1.0f / ((float)B * TEMP));

    #pragma unroll
    for (int off = 32; off > 0; off >>= 1) local += __shfl_xor(local, off);

    __shared__ float wsum[16];
    int wave = threadIdx.x >> 6, lane = threadIdx.x & 63;
    if (lane == 0) wsum[wave] = local;
    __syncthreads();
    if (threadIdx.x == 0) {
        float s = 0.f;
        for (int i = 0; i < 16; ++i) s += wsum[i];
        out[0] = s;
    }
}

extern "C" void kernel_launch(void* const* d_in, const int* in_sizes, int n_in,
                              void* d_out, int out_size, void* d_ws, size_t ws_size,
                              hipStream_t stream) {
    const float* p1 = (const float*)d_in[0];
    const float* p2 = (const float*)d_in[1];
    float* out = (float*)d_out;

    const int B  = in_sizes[0] / 128;   // 4096
    const int N2 = 2 * B;               // 8192

    // ws layout: [reps bf16: N2*256 B][rowsum fp32: N2*4 B][pos fp32: B*4 B]
    unsigned short* reps = (unsigned short*)d_ws;
    float* rowsum = (float*)((char*)d_ws + (size_t)N2 * 256);
    float* pos    = rowsum + N2;

    hipMemsetAsync(rowsum, 0, (size_t)N2 * sizeof(float), stream);

    norm_pos_kernel<<<dim3((B + 3) / 4), dim3(256), 0, stream>>>(p1, p2, reps, pos, B);

    dim3 grid(N2 / 256, N2 / 256);  // 32 x 32 = 1024 blocks
    simexp_kernel<<<grid, dim3(256), 0, stream>>>(reps, rowsum);

    finalize_kernel<<<dim3(1), dim3(1024), 0, stream>>>(rowsum, pos, out, N2, B);
}